// Round 2
// baseline (599.258 us; speedup 1.0000x reference)
//
#include <hip/hip_runtime.h>
#include <cstdint>
#include <cstddef>

#define TLEN    50
#define BATCH   16
#define D_IN    512
#define SRC_LEN 200
#define VOCAB   20000
#define CVOCAB  20400

typedef __bf16 bf16x8 __attribute__((ext_vector_type(8)));
typedef float  f32x4  __attribute__((ext_vector_type(4)));

#define TSPLIT  2
#define TCHUNK  (TLEN / TSPLIT)          // 25
#define COLTILES 157                      // ceil(20000/128)
#define GEMM_BLOCKS (COLTILES * TSPLIT)   // 314
#define ZERO_BLOCKS 40
#define SCAN_BLOCKS (SRC_LEN * BATCH)     // 3200
#define NTHREADS 256

// ---------------- kernel 0: p_copy[800] = sigmoid(hidden . Wc + bc) --------
__global__ __launch_bounds__(256)
void pc_kernel(const float* __restrict__ hidden,
               const float* __restrict__ Wc,
               const float* __restrict__ bc,
               float* __restrict__ pc)
{
    const int row  = blockIdx.x * 4 + (threadIdx.x >> 6);   // 0..799
    const int lane = threadIdx.x & 63;
    const float* h = hidden + (size_t)row * D_IN + lane * 8;
    float4 h0 = *(const float4*)(h);
    float4 h1 = *(const float4*)(h + 4);
    float4 w0 = *(const float4*)(Wc + lane * 8);
    float4 w1 = *(const float4*)(Wc + lane * 8 + 4);
    float s = h0.x*w0.x + h0.y*w0.y + h0.z*w0.z + h0.w*w0.w
            + h1.x*w1.x + h1.y*w1.y + h1.z*w1.z + h1.w*w1.w;
    #pragma unroll
    for (int o = 1; o < 64; o <<= 1) s += __shfl_xor(s, o);
    if (lane == 0) pc[row] = 1.0f / (1.0f + __expf(-(s + bc[0])));
}

// ---------------- kernel 1: fused GEMM+softmax / tail-zero / src_map scan --
// Barrier-free, LDS-free. Roles: [0,314) GEMM, [314,354) zero, [354,3554) scan.
__global__ __launch_bounds__(NTHREADS, 2)
void fused_main(const float* __restrict__ hidden,
                const float* __restrict__ src_map,
                const float* __restrict__ W,
                const float* __restrict__ pc,
                float* __restrict__ out,
                int* __restrict__ src_ids)
{
    const int bid = blockIdx.x;
    const int tid = threadIdx.x;

    if (bid < GEMM_BLOCKS) {
        // ---- GEMM (logits, bf16 MFMA) + softmax over batch + (1-pc) scale ----
        // Bias b[v] is uniform along the softmax (batch) axis -> cancels; unused.
        const int ct = bid / TSPLIT;            // col tile 0..156
        const int th = bid % TSPLIT;            // t half
        const int t0 = th * TCHUNK;

        const int lane = tid & 63;
        const int wv   = tid >> 6;              // 4 waves, 32 cols each
        const int l15  = lane & 15;
        const int q    = lane >> 4;             // quad
        const int colbase = ct * 128 + wv * 32;

        // B fragments: W rows (vocab cols of the GEMM) held for whole kernel.
        bf16x8 bfrag[2][16];
        bool act[2];
        {
            bf16x8 zf;
            #pragma unroll
            for (int j = 0; j < 8; ++j) zf[j] = (__bf16)0.0f;
            #pragma unroll
            for (int g = 0; g < 2; ++g) {
                const int vb = colbase + g * 16;
                act[g] = (vb < VOCAB);          // VOCAB%16==0: group all-valid or not
                #pragma unroll
                for (int c = 0; c < 16; ++c) bfrag[g][c] = zf;
                if (act[g]) {
                    const float* wrow = W + (size_t)(vb + l15) * D_IN + q * 8;
                    #pragma unroll
                    for (int c = 0; c < 16; ++c) {
                        float4 f0 = *(const float4*)(wrow + c * 32);
                        float4 f1 = *(const float4*)(wrow + c * 32 + 4);
                        bf16x8 bf;
                        bf[0] = (__bf16)f0.x; bf[1] = (__bf16)f0.y;
                        bf[2] = (__bf16)f0.z; bf[3] = (__bf16)f0.w;
                        bf[4] = (__bf16)f1.x; bf[5] = (__bf16)f1.y;
                        bf[6] = (__bf16)f1.z; bf[7] = (__bf16)f1.w;
                        bfrag[g][c] = bf;
                    }
                }
            }
        }

        for (int t = t0; t < t0 + TCHUNK; ++t) {
            // A fragments direct from global (hidden[t] is 32KB, L2-resident):
            // lane needs A[m=l15][k=q*8+c*32+j], i.e. 8 contiguous floats per c.
            const float* hbase = hidden + ((size_t)t * BATCH + l15) * D_IN + q * 8;
            f32x4 acc0 = {0.f, 0.f, 0.f, 0.f};
            f32x4 acc1 = {0.f, 0.f, 0.f, 0.f};
            #pragma unroll
            for (int c = 0; c < 16; ++c) {
                float4 f0 = *(const float4*)(hbase + c * 32);
                float4 f1 = *(const float4*)(hbase + c * 32 + 4);
                bf16x8 af;
                af[0] = (__bf16)f0.x; af[1] = (__bf16)f0.y;
                af[2] = (__bf16)f0.z; af[3] = (__bf16)f0.w;
                af[4] = (__bf16)f1.x; af[5] = (__bf16)f1.y;
                af[6] = (__bf16)f1.z; af[7] = (__bf16)f1.w;
                acc0 = __builtin_amdgcn_mfma_f32_16x16x32_bf16(af, bfrag[0][c], acc0, 0, 0, 0);
                acc1 = __builtin_amdgcn_mfma_f32_16x16x32_bf16(af, bfrag[1][c], acc1, 0, 0, 0);
            }
            // pc for this lane's 4 batch rows (b = q*4+r)
            float4 pc4 = *(const float4*)(pc + t * 16 + q * 4);

            // softmax over batch (the D rows), b==1 masked to prob 0
            #pragma unroll
            for (int g = 0; g < 2; ++g) {
                f32x4 acc = g ? acc1 : acc0;
                float mx = -INFINITY;
                #pragma unroll
                for (int r = 0; r < 4; ++r)
                    if (q * 4 + r != 1) mx = fmaxf(mx, acc[r]);
                mx = fmaxf(mx, __shfl_xor(mx, 16));
                mx = fmaxf(mx, __shfl_xor(mx, 32));
                float e[4], s = 0.f;
                #pragma unroll
                for (int r = 0; r < 4; ++r) {
                    e[r] = (q * 4 + r == 1) ? 0.f : __expf(acc[r] - mx);
                    s += e[r];
                }
                s += __shfl_xor(s, 16);
                s += __shfl_xor(s, 32);
                const float inv = 1.0f / s;
                if (act[g]) {
                    const int v = colbase + g * 16 + l15;
                    #pragma unroll
                    for (int r = 0; r < 4; ++r) {
                        const int b = q * 4 + r;
                        out[(size_t)(t * BATCH + b) * CVOCAB + v] =
                            e[r] * inv * (1.0f - pc4[r]);
                    }
                }
            }
        }
    } else if (bid < GEMM_BLOCKS + ZERO_BLOCKS) {
        // ---- zero extended-vocab tail cols [20000,20400) of all 800 rows ----
        const int zb = bid - GEMM_BLOCKS;
        const float4 z = {0.f, 0.f, 0.f, 0.f};
        for (int i = tid; i < 2000; i += NTHREADS) {
            const int f = zb * 2000 + i;       // 0..79999 float4s, 100 per row
            const int r = f / 100;
            const int c = f % 100;
            *(float4*)(out + (size_t)r * CVOCAB + VOCAB + c * 4) = z;
        }
    } else {
        // ---- scan one one-hot src_map row (20400 fp32) -> index ----
        const int row = bid - GEMM_BLOCKS - ZERO_BLOCKS;   // (s*16+b)
        const float4* base = (const float4*)(src_map + (size_t)row * CVOCAB);
        int found = -1;
        for (int i0 = tid; i0 < 1275; i0 += NTHREADS) {
            float4 x0 = base[i0];
            float4 x1 = base[i0 + 1275];
            float4 x2 = base[i0 + 2550];
            float4 x3 = base[i0 + 3825];
            #pragma unroll
            for (int seg = 0; seg < 4; ++seg) {
                float4 x = seg == 0 ? x0 : seg == 1 ? x1 : seg == 2 ? x2 : x3;
                const int e0 = (i0 + seg * 1275) * 4;
                if (x.x > 0.5f) found = e0;
                if (x.y > 0.5f) found = e0 + 1;
                if (x.z > 0.5f) found = e0 + 2;
                if (x.w > 0.5f) found = e0 + 3;
            }
        }
        if (found >= 0) src_ids[row] = found;  // exactly one finder per row
    }
}

// ---------------- kernel 2: scatter copy-probs --------------------------------
// r=t*16+b; reference's split/stack/transpose sends copy_prob[t,b,:] to
// output row (t'=r%50, b'=r/50). atomicAdd onto already-written out_prob.
__global__ __launch_bounds__(256)
void scatter_copy(const float* __restrict__ attn,
                  const float* __restrict__ pc,
                  const int* __restrict__ src_ids,
                  float* __restrict__ out)
{
    const int p  = blockIdx.x;             // 0..799
    const int si = threadIdx.x;
    if (si >= SRC_LEN) return;
    const int b  = p & 15;
    const size_t obase = (size_t)((p % TLEN) * BATCH + (p / TLEN)) * CVOCAB;
    const int id = src_ids[si * BATCH + b];
    const float val = attn[(size_t)p * SRC_LEN + si] * pc[p];
    if ((unsigned)id < (unsigned)CVOCAB)
        atomicAdd(out + obase + id, val);
}

extern "C" void kernel_launch(void* const* d_in, const int* in_sizes, int n_in,
                              void* d_out, int out_size, void* d_ws, size_t ws_size,
                              hipStream_t stream)
{
    const float* hidden  = (const float*)d_in[0];  // (50,16,512)
    const float* attn    = (const float*)d_in[1];  // (50,16,200)
    const float* src_map = (const float*)d_in[2];  // (200,16,20400) one-hot
    const float* W       = (const float*)d_in[3];  // (20000,512)
    // d_in[4] = b (20000): cancels in softmax over batch -> unused
    const float* Wc      = (const float*)d_in[5];  // (1,512)
    const float* bc      = (const float*)d_in[6];  // (1,)
    float* out   = (float*)d_out;                  // (50,16,20400)
    int* src_ids = (int*)d_ws;                     // 3200 ints
    float* pc    = (float*)d_ws + 3200;            // 800 floats

    pc_kernel<<<dim3(200), dim3(256), 0, stream>>>(hidden, Wc, bc, pc);
    fused_main<<<dim3(GEMM_BLOCKS + ZERO_BLOCKS + SCAN_BLOCKS), dim3(NTHREADS), 0, stream>>>(
        hidden, src_map, W, pc, out, src_ids);
    scatter_copy<<<dim3(TLEN * BATCH), dim3(256), 0, stream>>>(attn, pc, src_ids, out);
}

// Round 3
// 438.413 us; speedup vs baseline: 1.3669x; 1.3669x over previous
//
#include <hip/hip_runtime.h>
#include <cstdint>
#include <cstddef>

#define TLEN    50
#define BATCH   16
#define D_IN    512
#define SRC_LEN 200
#define VOCAB   20000
#define CVOCAB  20400

typedef __bf16 bf16x8 __attribute__((ext_vector_type(8)));
typedef float  f32x4  __attribute__((ext_vector_type(4)));

#define GEMM_BLOCKS 625                   // 32 vocab cols per block (2 waves x 16)
#define ZERO_BLOCKS 40
#define SCAN_BLOCKS (SRC_LEN * BATCH)     // 3200
#define NT 128                            // 2 waves per block
#define APAD 8                            // row stride 520 bf16 = 65 qwords (odd mod 8)

// ---------------- kernel 0: p_copy[800] = sigmoid(hidden . Wc + bc) --------
__global__ __launch_bounds__(256)
void pc_kernel(const float* __restrict__ hidden,
               const float* __restrict__ Wc,
               const float* __restrict__ bc,
               float* __restrict__ pc)
{
    const int row  = blockIdx.x * 4 + (threadIdx.x >> 6);   // 0..799
    const int lane = threadIdx.x & 63;
    const float* h = hidden + (size_t)row * D_IN + lane * 8;
    float4 h0 = *(const float4*)(h);
    float4 h1 = *(const float4*)(h + 4);
    float4 w0 = *(const float4*)(Wc + lane * 8);
    float4 w1 = *(const float4*)(Wc + lane * 8 + 4);
    float s = h0.x*w0.x + h0.y*w0.y + h0.z*w0.z + h0.w*w0.w
            + h1.x*w1.x + h1.y*w1.y + h1.z*w1.z + h1.w*w1.w;
    #pragma unroll
    for (int o = 1; o < 64; o <<= 1) s += __shfl_xor(s, o);
    if (lane == 0) pc[row] = 1.0f / (1.0f + __expf(-(s + bc[0])));
}

// ---------------- kernel 1: fused GEMM+softmax / tail-zero / src_map scan --
// Roles: [0,625) GEMM (long blocks, dispatched first), [625,665) zero,
// [665,3865) scan.
__global__ __launch_bounds__(NT)
void fused_main(const float* __restrict__ hidden,
                const float* __restrict__ src_map,
                const float* __restrict__ W,
                const float* __restrict__ pc,
                float* __restrict__ out,
                int* __restrict__ src_ids)
{
    const int bid = blockIdx.x;
    const int tid = threadIdx.x;

    if (bid < GEMM_BLOCKS) {
        // ---- GEMM (logits, bf16 MFMA) + softmax over batch + (1-pc) scale ----
        // b[v] bias is uniform along the softmax (batch) axis -> cancels; unused.
        __shared__ __bf16 Alds[2][BATCH][D_IN + APAD];

        const int lane = tid & 63;
        const int wv   = tid >> 6;            // 0..1
        const int l15  = lane & 15;
        const int q    = lane >> 4;
        const int colbase = bid * 32 + wv * 16;   // 625*32 == 20000 exactly

        // B fragments: 16 cols x 512 k -> 16 x bf16x8 = 64 VGPRs. Loaded ONCE
        // from HBM, then PINNED via empty asm so LLVM cannot sink the loads
        // into the t-loop (R2 pathology: VGPR=80 proved W was re-read 25x).
        bf16x8 bfrag[16];
        {
            const float* wrow = W + (size_t)(colbase + l15) * D_IN + q * 8;
            #pragma unroll
            for (int c = 0; c < 16; ++c) {
                float4 f0 = *(const float4*)(wrow + c * 32);
                float4 f1 = *(const float4*)(wrow + c * 32 + 4);
                bf16x8 bf;
                bf[0] = (__bf16)f0.x; bf[1] = (__bf16)f0.y;
                bf[2] = (__bf16)f0.z; bf[3] = (__bf16)f0.w;
                bf[4] = (__bf16)f1.x; bf[5] = (__bf16)f1.y;
                bf[6] = (__bf16)f1.z; bf[7] = (__bf16)f1.w;
                bfrag[c] = bf;
            }
            #pragma unroll
            for (int c = 0; c < 16; ++c) {
                f32x4 t = *(f32x4*)&bfrag[c];
                asm volatile("" : "+v"(t));
                bfrag[c] = *(bf16x8*)&t;
            }
        }

        // stage hidden[t] into buf: thread stages row i=0..15, cols tid*4..+3
        auto stage = [&](int t, int buf) {
            #pragma unroll
            for (int i = 0; i < 16; ++i) {
                float4 v4 = *(const float4*)(hidden + ((size_t)t * BATCH + i) * D_IN + tid * 4);
                __bf16* dst = &Alds[buf][i][tid * 4];
                dst[0] = (__bf16)v4.x; dst[1] = (__bf16)v4.y;
                dst[2] = (__bf16)v4.z; dst[3] = (__bf16)v4.w;
            }
        };

        stage(0, 0);

        for (int t = 0; t < TLEN; ++t) {
            __syncthreads();                       // staged(t) visible; buf[(t+1)&1] readers (t-1) done
            if (t + 1 < TLEN) stage(t + 1, (t + 1) & 1);

            const __bf16* arow = &Alds[t & 1][l15][q * 8];
            f32x4 accA = {0.f, 0.f, 0.f, 0.f};
            f32x4 accB = {0.f, 0.f, 0.f, 0.f};
            #pragma unroll
            for (int c = 0; c < 16; c += 2) {
                bf16x8 a0 = *(const bf16x8*)(arow + c * 32);
                bf16x8 a1 = *(const bf16x8*)(arow + c * 32 + 32);
                accA = __builtin_amdgcn_mfma_f32_16x16x32_bf16(a0, bfrag[c],     accA, 0, 0, 0);
                accB = __builtin_amdgcn_mfma_f32_16x16x32_bf16(a1, bfrag[c + 1], accB, 0, 0, 0);
            }
            f32x4 acc = accA + accB;

            float4 pc4 = *(const float4*)(pc + t * 16 + q * 4);

            // softmax over batch (D rows), b==1 masked to prob 0
            float mx = -INFINITY;
            #pragma unroll
            for (int r = 0; r < 4; ++r)
                if (q * 4 + r != 1) mx = fmaxf(mx, acc[r]);
            mx = fmaxf(mx, __shfl_xor(mx, 16));
            mx = fmaxf(mx, __shfl_xor(mx, 32));
            float e[4], s = 0.f;
            #pragma unroll
            for (int r = 0; r < 4; ++r) {
                e[r] = (q * 4 + r == 1) ? 0.f : __expf(acc[r] - mx);
                s += e[r];
            }
            s += __shfl_xor(s, 16);
            s += __shfl_xor(s, 32);
            const float inv = 1.0f / s;
            const int v = colbase + l15;
            #pragma unroll
            for (int r = 0; r < 4; ++r) {
                const int b = q * 4 + r;
                out[(size_t)(t * BATCH + b) * CVOCAB + v] = e[r] * inv * (1.0f - pc4[r]);
            }
        }
    } else if (bid < GEMM_BLOCKS + ZERO_BLOCKS) {
        // ---- zero extended-vocab tail cols [20000,20400) of all 800 rows ----
        const int zb = bid - GEMM_BLOCKS;
        const float4 z = {0.f, 0.f, 0.f, 0.f};
        for (int i = tid; i < 2000; i += NT) {
            const int f = zb * 2000 + i;          // 0..79999 float4s, 100 per row
            const int r = f / 100;
            const int c = f % 100;
            *(float4*)(out + (size_t)r * CVOCAB + VOCAB + c * 4) = z;
        }
    } else {
        // ---- scan one one-hot src_map row (20400 fp32) -> index ----
        const int row = bid - GEMM_BLOCKS - ZERO_BLOCKS;   // (s*16+b)
        const float4* base = (const float4*)(src_map + (size_t)row * CVOCAB);
        int found = -1;
        for (int i0 = tid; i0 < 1275; i0 += NT) {
            float4 x0 = base[i0];
            float4 x1 = base[i0 + 1275];
            float4 x2 = base[i0 + 2550];
            float4 x3 = base[i0 + 3825];
            #pragma unroll
            for (int seg = 0; seg < 4; ++seg) {
                float4 x = seg == 0 ? x0 : seg == 1 ? x1 : seg == 2 ? x2 : x3;
                const int e0 = (i0 + seg * 1275) * 4;
                if (x.x > 0.5f) found = e0;
                if (x.y > 0.5f) found = e0 + 1;
                if (x.z > 0.5f) found = e0 + 2;
                if (x.w > 0.5f) found = e0 + 3;
            }
        }
        if (found >= 0) src_ids[row] = found;     // exactly one finder per row
    }
}

// ---------------- kernel 2: scatter copy-probs ------------------------------
// r=t*16+b; reference's split/stack/transpose sends copy_prob[t,b,:] to
// output row (t'=r%50, b'=r/50). atomicAdd onto already-written out_prob.
__global__ __launch_bounds__(256)
void scatter_copy(const float* __restrict__ attn,
                  const float* __restrict__ pc,
                  const int* __restrict__ src_ids,
                  float* __restrict__ out)
{
    const int p  = blockIdx.x;             // 0..799
    const int si = threadIdx.x;
    if (si >= SRC_LEN) return;
    const int b  = p & 15;
    const size_t obase = (size_t)((p % TLEN) * BATCH + (p / TLEN)) * CVOCAB;
    const int id = src_ids[si * BATCH + b];
    const float val = attn[(size_t)p * SRC_LEN + si] * pc[p];
    if ((unsigned)id < (unsigned)CVOCAB)
        atomicAdd(out + obase + id, val);
}

extern "C" void kernel_launch(void* const* d_in, const int* in_sizes, int n_in,
                              void* d_out, int out_size, void* d_ws, size_t ws_size,
                              hipStream_t stream)
{
    const float* hidden  = (const float*)d_in[0];  // (50,16,512)
    const float* attn    = (const float*)d_in[1];  // (50,16,200)
    const float* src_map = (const float*)d_in[2];  // (200,16,20400) one-hot
    const float* W       = (const float*)d_in[3];  // (20000,512)
    // d_in[4] = b (20000): cancels in softmax over batch -> unused
    const float* Wc      = (const float*)d_in[5];  // (1,512)
    const float* bc      = (const float*)d_in[6];  // (1,)
    float* out   = (float*)d_out;                  // (50,16,20400)
    int* src_ids = (int*)d_ws;                     // 3200 ints
    float* pc    = (float*)d_ws + 3200;            // 800 floats

    pc_kernel<<<dim3(200), dim3(256), 0, stream>>>(hidden, Wc, bc, pc);
    fused_main<<<dim3(GEMM_BLOCKS + ZERO_BLOCKS + SCAN_BLOCKS), dim3(NT), 0, stream>>>(
        hidden, src_map, W, pc, out, src_ids);
    scatter_copy<<<dim3(TLEN * BATCH), dim3(256), 0, stream>>>(attn, pc, src_ids, out);
}